// Round 4
// baseline (391.012 us; speedup 1.0000x reference)
//
#include <hip/hip_runtime.h>
#include <hip/hip_bf16.h>

#define DIM 64
#define RELS 32
#define SCAN_B 512

// ---- Precompute M[v][r] = dot(ent[v], rel[r]) * 0.125 as bf16 (12.8 MB, L2-resident) ----
__global__ __launch_bounds__(256) void build_M(
    const float* __restrict__ ent, const float* __restrict__ rel,
    __hip_bfloat16* __restrict__ M, int nE) {
    int r  = threadIdx.x & 31;       // relation id
    int vg = threadIdx.x >> 5;       // 0..7
    int base = blockIdx.x * 64;
    const float4* rel4 = (const float4*)rel;
    const float4* ent4 = (const float4*)ent;
    float4 relreg[16];
    #pragma unroll
    for (int d4 = 0; d4 < 16; d4++) relreg[d4] = rel4[r * 16 + d4];
    #pragma unroll
    for (int k = 0; k < 8; k++) {
        int v = base + vg + 8 * k;
        if (v < nE) {
            float acc = 0.f;
            #pragma unroll
            for (int d4 = 0; d4 < 16; d4++) {
                float4 a = ent4[(size_t)v * 16 + d4];
                acc += a.x * relreg[d4].x + a.y * relreg[d4].y
                     + a.z * relreg[d4].z + a.w * relreg[d4].w;
            }
            M[(size_t)v * RELS + r] = __float2bfloat16(acc * 0.125f);
        }
    }
}

// ---- Degree histogram + stable ranks (no embeddings needed) ----
__global__ __launch_bounds__(256) void deg_count(
    const int* __restrict__ head, const int* __restrict__ uidx,
    unsigned int* __restrict__ deg,
    unsigned int* __restrict__ rank_e, unsigned int* __restrict__ rank_i,
    int E, int I, int nE) {
    int t = blockIdx.x * blockDim.x + threadIdx.x;
    if (t < E) rank_e[t] = atomicAdd(&deg[head[t]], 1u);
    else if (t < E + I) { int e = t - E; rank_i[e] = atomicAdd(&deg[nE + uidx[e]], 1u); }
}

// ---- Scan step 1 ----
__global__ __launch_bounds__(SCAN_B) void scan_partial(
    const unsigned int* __restrict__ deg, unsigned int* __restrict__ part, int n) {
    __shared__ unsigned int lds[SCAN_B];
    int i = blockIdx.x * SCAN_B + threadIdx.x;
    lds[threadIdx.x] = (i < n) ? deg[i] : 0u;
    __syncthreads();
    for (int off = SCAN_B >> 1; off > 0; off >>= 1) {
        if (threadIdx.x < off) lds[threadIdx.x] += lds[threadIdx.x + off];
        __syncthreads();
    }
    if (threadIdx.x == 0) part[blockIdx.x] = lds[0];
}

// ---- Scan step 2 ----
__global__ __launch_bounds__(1024) void scan_block(unsigned int* __restrict__ part, int nb) {
    __shared__ unsigned int lds[1024];
    int t = threadIdx.x;
    unsigned int v = (t < nb) ? part[t] : 0u;
    lds[t] = v;
    __syncthreads();
    for (int off = 1; off < 1024; off <<= 1) {
        unsigned int x = (t >= off) ? lds[t - off] : 0u;
        __syncthreads();
        lds[t] += x;
        __syncthreads();
    }
    if (t < nb) part[t] = lds[t] - v;
}

// ---- Scan step 3 ----
__global__ __launch_bounds__(SCAN_B) void scan_final(
    const unsigned int* __restrict__ deg, const unsigned int* __restrict__ part,
    unsigned int* __restrict__ offs, int n) {
    __shared__ unsigned int lds[SCAN_B];
    int t = threadIdx.x;
    int i = blockIdx.x * SCAN_B + t;
    unsigned int v = (i < n) ? deg[i] : 0u;
    lds[t] = v;
    __syncthreads();
    for (int off = 1; off < SCAN_B; off <<= 1) {
        unsigned int x = (t >= off) ? lds[t - off] : 0u;
        __syncthreads();
        lds[t] += x;
        __syncthreads();
    }
    if (i < n) offs[i] = part[blockIdx.x] + lds[t] - v;
}

// ---- Fused score (table lookup) + atomic-free scatter of CSR payloads ----
__global__ __launch_bounds__(256) void score_scatter(
    const __hip_bfloat16* __restrict__ M,
    const int* __restrict__ head, const int* __restrict__ tail, const int* __restrict__ etype,
    const int* __restrict__ uidx, const int* __restrict__ iidx, const int* __restrict__ ttype,
    const unsigned int* __restrict__ rank_e, const unsigned int* __restrict__ rank_i,
    const unsigned int* __restrict__ offs,
    unsigned long long* __restrict__ pay, unsigned int* __restrict__ payu,
    int E, int I, int nE) {
    int t = blockIdx.x * blockDim.x + threadIdx.x;
    if (t < E) {
        int tl = tail[t];
        float sc = __bfloat162float(M[(size_t)tl * RELS + (etype[t] - 1)]);
        unsigned int p = offs[head[t]] + rank_e[t];
        unsigned long long v = ((unsigned long long)(unsigned int)__float_as_int(sc) << 32)
                             | (unsigned int)tl;
        __builtin_nontemporal_store(v, &pay[p]);
    } else if (t < E + I) {
        int e = t - E;
        unsigned int p = offs[nE + uidx[e]] + rank_i[e] - (unsigned)E;
        unsigned int v = (unsigned int)iidx[e] | ((unsigned int)ttype[e] << 27);
        __builtin_nontemporal_store(v, &payu[p]);
    }
}

// ---- Entity: online-softmax weighted gather-accumulate, 2-deep prefetch ----
__global__ __launch_bounds__(256) void agg_entity(
    const float* __restrict__ emb, const unsigned long long* __restrict__ pay,
    const unsigned int* __restrict__ deg, const unsigned int* __restrict__ offs,
    float2* __restrict__ msum, float* __restrict__ agg, int nSeg) {
    int t = blockIdx.x * blockDim.x + threadIdx.x;
    int h = t >> 4, l = t & 15;
    if (h >= nSeg) return;
    unsigned int d = deg[h];
    float m = -3.0e38f, s = 0.f, inv = 0.f;
    float4 acc = make_float4(0.f, 0.f, 0.f, 0.f);
    if (d) {
        unsigned int off = offs[h];
        unsigned long long v0 = pay[off];
        float4 a0 = ((const float4*)(emb + (size_t)(unsigned int)(v0 & 0xffffffffu) * DIM))[l];
        for (unsigned int j = 0; j < d; j++) {
            unsigned long long v1 = v0; float4 a1 = a0;
            if (j + 1 < d) {
                v1 = pay[off + j + 1];
                a1 = ((const float4*)(emb + (size_t)(unsigned int)(v1 & 0xffffffffu) * DIM))[l];
            }
            float sc = __int_as_float((int)(v0 >> 32));
            float mn = fmaxf(m, sc);
            float scale = __expf(m - mn);
            float w = __expf(sc - mn);
            s = s * scale + w;
            acc.x = acc.x * scale + w * a0.x;
            acc.y = acc.y * scale + w * a0.y;
            acc.z = acc.z * scale + w * a0.z;
            acc.w = acc.w * scale + w * a0.w;
            m = mn; v0 = v1; a0 = a1;
        }
        inv = 1.f / s;
    }
    if (l == 0) msum[h] = make_float2(m, inv);
    acc.x *= inv; acc.y *= inv; acc.z *= inv; acc.w *= inv;
    ((float4*)(agg + (size_t)h * DIM))[l] = acc;
}

// ---- User: fused score + online softmax + aggregate (usr row loaded once) ----
__global__ __launch_bounds__(256) void user_fused(
    const float* __restrict__ ent, const float* __restrict__ usr,
    const float* __restrict__ itc, const unsigned int* __restrict__ payu,
    const unsigned int* __restrict__ deg, const unsigned int* __restrict__ offs,
    int nE, int E, float* __restrict__ patt, float2* __restrict__ msum,
    float* __restrict__ agg, int nU) {
    __shared__ float4 itcL[8][16];
    int tx = threadIdx.x;
    if (tx < 128) itcL[tx >> 4][tx & 15] = ((const float4*)itc)[tx];
    __syncthreads();
    int t = blockIdx.x * blockDim.x + tx;
    int h = t >> 4, l = t & 15;
    if (h >= nU) return;
    unsigned int d = deg[nE + h];
    float m = -3.0e38f, s = 0.f, inv = 0.f;
    float4 acc = make_float4(0.f, 0.f, 0.f, 0.f);
    float4 ur = ((const float4*)(usr + (size_t)h * DIM))[l];
    if (d) {
        unsigned int off = offs[nE + h] - (unsigned)E;
        unsigned int v0 = payu[off];
        float4 a0 = ((const float4*)(ent + (size_t)(v0 & 0x7ffffffu) * DIM))[l];
        for (unsigned int j = 0; j < d; j++) {
            unsigned int v1 = v0; float4 a1 = a0;
            if (j + 1 < d) {
                v1 = payu[off + j + 1];
                a1 = ((const float4*)(ent + (size_t)(v1 & 0x7ffffffu) * DIM))[l];
            }
            float4 c = itcL[v0 >> 27][l];
            float p = a0.x * ur.x * c.x + a0.y * ur.y * c.y
                    + a0.z * ur.z * c.z + a0.w * ur.w * c.w;
            p += __shfl_xor(p, 1);
            p += __shfl_xor(p, 2);
            p += __shfl_xor(p, 4);
            p += __shfl_xor(p, 8);
            if (l == 0) patt[off + j] = p;
            float mn = fmaxf(m, p);
            float scale = __expf(m - mn);
            float w = __expf(p - mn);
            s = s * scale + w;
            acc.x = acc.x * scale + w * a0.x;
            acc.y = acc.y * scale + w * a0.y;
            acc.z = acc.z * scale + w * a0.z;
            acc.w = acc.w * scale + w * a0.w;
            m = mn; v0 = v1; a0 = a1;
        }
        inv = 1.f / s;
    }
    if (l == 0) msum[nE + h] = make_float2(m, inv);
    acc.x *= inv; acc.y *= inv; acc.z *= inv; acc.w *= inv;
    ((float4*)(agg + (size_t)h * DIM))[l] = acc;
}

// ---- Epilogue: coalesced per-edge weight writes ----
__global__ __launch_bounds__(256) void wout(
    const int* __restrict__ head, const int* __restrict__ uidx,
    const unsigned long long* __restrict__ pay, const float* __restrict__ patt,
    const unsigned int* __restrict__ rank_e, const unsigned int* __restrict__ rank_i,
    const unsigned int* __restrict__ offs, const float2* __restrict__ msum,
    float* __restrict__ w1, float* __restrict__ attw, int E, int I, int nE) {
    int t = blockIdx.x * blockDim.x + threadIdx.x;
    if (t < E) {
        int hd = head[t];
        float2 mi = msum[hd];
        unsigned long long v = pay[offs[hd] + rank_e[t]];
        w1[t] = __expf(__int_as_float((int)(v >> 32)) - mi.x) * mi.y;
    } else if (t < E + I) {
        int e = t - E; int u = uidx[e];
        float2 mi = msum[nE + u];
        float sc = patt[offs[nE + u] - (unsigned)E + rank_i[e]];
        attw[e] = __expf(sc - mi.x) * mi.y;
    }
}

extern "C" void kernel_launch(void* const* d_in, const int* in_sizes, int n_in,
                              void* d_out, int out_size, void* d_ws, size_t ws_size,
                              hipStream_t stream) {
    const float* ent  = (const float*)d_in[0];
    const float* usr  = (const float*)d_in[1];
    const float* itc  = (const float*)d_in[2];
    const float* rel  = (const float*)d_in[3];
    const int* eidx   = (const int*)d_in[4];
    const int* etype  = (const int*)d_in[5];
    const int* uidx   = (const int*)d_in[6];
    const int* iidx   = (const int*)d_in[7];
    const int* ttype  = (const int*)d_in[8];

    const int E  = in_sizes[4] / 2;
    const int I  = in_sizes[6];
    const int nE = in_sizes[0] / DIM;
    const int nU = in_sizes[1] / DIM;
    const int* head = eidx;
    const int* tail = eidx + E;
    const int NSEG = nE + nU;
    const int NB = (NSEG + SCAN_B - 1) / SCAN_B;   // <= 1024

    float* out_entity = (float*)d_out;
    float* out_user   = out_entity + (size_t)nE * DIM;
    float* out_attw   = out_user + (size_t)nU * DIM;
    float* out_w1     = out_attw + I;

    // workspace layout (word offsets even where 8B alignment needed)
    unsigned int* deg     = (unsigned int*)d_ws;            // NSEG
    unsigned int* offs    = deg + NSEG;                     // NSEG
    unsigned int* part    = offs + NSEG;                    // 1024
    unsigned int* rank_e  = part + 1024;                    // E
    unsigned int* rank_i  = rank_e + E;                     // I
    unsigned long long* pay = (unsigned long long*)(rank_i + I);  // E u64
    unsigned int* payu    = (unsigned int*)(pay + E);       // I
    // M region (nE*RELS bf16 = nE*16 words), dead after score_scatter;
    // msum + patt alias into it afterwards.
    __hip_bfloat16* M = (__hip_bfloat16*)(payu + I);
    float2* msum = (float2*)(payu + I);                     // NSEG float2
    float* patt  = (float*)(msum + NSEG);                   // I floats

    hipMemsetAsync(deg, 0, (size_t)NSEG * sizeof(unsigned int), stream);

    const int T = 256;
    dim3 gM((unsigned)((nE + 63) / 64));
    dim3 gEI((unsigned)((E + I + T - 1) / T));
    dim3 gAE((unsigned)(((size_t)nE * 16 + T - 1) / T));
    dim3 gAU((unsigned)(((size_t)nU * 16 + T - 1) / T));

    build_M<<<gM, T, 0, stream>>>(ent, rel, M, nE);
    deg_count<<<gEI, T, 0, stream>>>(head, uidx, deg, rank_e, rank_i, E, I, nE);

    scan_partial<<<dim3((unsigned)NB), SCAN_B, 0, stream>>>(deg, part, NSEG);
    scan_block<<<dim3(1), 1024, 0, stream>>>(part, NB);
    scan_final<<<dim3((unsigned)NB), SCAN_B, 0, stream>>>(deg, part, offs, NSEG);

    score_scatter<<<gEI, T, 0, stream>>>(M, head, tail, etype, uidx, iidx, ttype,
                                         rank_e, rank_i, offs, pay, payu, E, I, nE);

    agg_entity<<<gAE, T, 0, stream>>>(ent, pay, deg, offs, msum, out_entity, nE);
    user_fused<<<gAU, T, 0, stream>>>(ent, usr, itc, payu, deg, offs, nE, E,
                                      patt, msum, out_user, nU);

    wout<<<gEI, T, 0, stream>>>(head, uidx, pay, patt, rank_e, rank_i, offs, msum,
                                out_w1, out_attw, E, I, nE);
}